// Round 20
// baseline (1715.893 us; speedup 1.0000x reference)
//
#include <hip/hip_runtime.h>
#include <math.h>

typedef unsigned int u32;
typedef unsigned short u16;
typedef unsigned long long u64;
typedef __attribute__((ext_vector_type(8))) short short8;
typedef __attribute__((ext_vector_type(4))) float f32x4;

__device__ inline float bf2f(u16 v) { return __uint_as_float(((u32)v) << 16); }
__device__ inline u16 f2bf(float f) {
  u32 u = __float_as_uint(f);
  return (u16)((u + 0x7fffu + ((u >> 16) & 1u)) >> 16);
}
__device__ inline float fast_tanh(float x) {
  x = fminf(9.0f, fmaxf(-9.0f, x));
  float e = __builtin_amdgcn_exp2f(x * 2.8853900817779268f);
  return (e - 1.0f) * __builtin_amdgcn_rcpf(e + 1.0f);
}
__device__ inline void gload16(const void* g, void* l) {
  __builtin_amdgcn_global_load_lds((const __attribute__((address_space(1))) u32*)g,
                                   (__attribute__((address_space(3))) u32*)l, 16, 0, 0);
}

// XCD-local tile mapping (128x128 tiles): row-panel m = blk&63 -> XCD m%8.
__device__ inline void tile_map(int blk, int& m0, int& n0) {
  n0 = (blk >> 6) << 7;
  m0 = (blk & 63) << 7;
}

// ======== prep kernels ========
__global__ void k_prep1(u16* __restrict__ xhi, u16* __restrict__ xlo,
                        const float* __restrict__ inp, const float* __restrict__ tag,
                        const float* __restrict__ sent,
                        u16* __restrict__ w0hi, u16* __restrict__ w0lo,
                        const float* __restrict__ g0wih,
                        float* __restrict__ wt0, const float* __restrict__ g0whh,
                        float* __restrict__ wt1, const float* __restrict__ g1whh,
                        u16* __restrict__ g1hi, u16* __restrict__ g1lo,
                        const float* __restrict__ g1wih) {
  int blk = blockIdx.x, t = threadIdx.x;
  if (blk < 32768) {
    int gid = blk * 256 + t;
    int row = gid >> 10, c = gid & 1023;
    int b = row >> 8, s = row & 255;
    float v;
    if (s == 0) v = sent[c];
    else if (c < 768) v = inp[(size_t)(b * 255 + s - 1) * 768 + c];
    else v = tag[(size_t)(b * 255 + s - 1) * 256 + (c - 768)];
    u16 h = f2bf(v);
    xhi[gid] = h;
    xlo[gid] = f2bf(v - bf2f(h));
  } else if (blk < 34816) {
    int i = (blk - 32768) * 256 + t;
    float v = g0wih[i];
    u16 h = f2bf(v);
    w0hi[i] = h;
    w0lo[i] = f2bf(v - bf2f(h));
  } else if (blk < 35840) {
    int i = (blk - 34816) * 256 + t;
    int k = i & 511, tt = i >> 9;
    wt0[(size_t)k * 512 + tt] = g0whh[(size_t)tt * 512 + k];
  } else if (blk < 36864) {
    int i = (blk - 35840) * 256 + t;
    int k = i & 511, tt = i >> 9;
    wt1[(size_t)k * 512 + tt] = g1whh[(size_t)tt * 512 + k];
  } else {
    int i = (blk - 36864) * 256 + t;
    float v = g1wih[i];
    u16 h = f2bf(v);
    g1hi[i] = h;
    g1lo[i] = f2bf(v - bf2f(h));
  }
}

__global__ void k_prep2(u64* __restrict__ hbuf,
                        u16* __restrict__ w0b, const float* __restrict__ e0whh,
                        u16* __restrict__ w1b, const float* __restrict__ e1wih,
                        u16* __restrict__ w2b, const float* __restrict__ e1whh,
                        u16* __restrict__ w3b, const float* __restrict__ htw,
                        u16* __restrict__ w4b, const float* __restrict__ dtw,
                        float* __restrict__ abuf, const float* __restrict__ clsb) {
  int blk = blockIdx.x, t = threadIdx.x;
  if (blk < 128) {
    int i = blk * 256 + t;
    int pos = i & 1023;
    hbuf[i] = (pos < 512) ? (1ull << 32) : 0ull;
  } else if (blk < 1152) {
    int i = (blk - 128) * 256 + t;  w0b[i] = f2bf(e0whh[i]);
  } else if (blk < 2176) {
    int i = (blk - 1152) * 256 + t; w1b[i] = f2bf(e1wih[i]);
  } else if (blk < 3200) {
    int i = (blk - 2176) * 256 + t; w2b[i] = f2bf(e1whh[i]);
  } else if (blk < 3712) {
    int i = (blk - 3200) * 256 + t; w3b[i] = f2bf(htw[i]);
  } else if (blk < 4224) {
    int i = (blk - 3712) * 256 + t; w4b[i] = f2bf(dtw[i]);
  } else {
    int i = (blk - 4224) * 256 + t;
    if (i < 212992) abuf[i] = ((i % 26) == 0) ? 1.0f : clsb[0];
  }
}

__global__ void k_prep3(u64* __restrict__ hbuf) {
  int i = blockIdx.x * 256 + threadIdx.x;
  int pos = i & 1023;
  hbuf[i] = (pos < 512) ? (1ull << 32) : 0ull;
}

// ======== multi-block g-RNN scan (verified round 19) ========
__global__ __launch_bounds__(512, 1) void k_gscan_mb(
    const float* __restrict__ XW, const float* __restrict__ WT,
    const int* __restrict__ mask, int layer, u64* hbuf,
    u16* __restrict__ o16a, u16* __restrict__ o16b)
{
  __shared__ float hls[2][528];
  const int blk = blockIdx.x;
  const int b = blk >> 2, q = blk & 3;
  const int tid = threadIdx.x;
  const int lane = tid & 63;
  const int wv = tid >> 6;
  const int colL = wv * 16 + (lane & 15);
  const int p = (lane >> 4) & 3;
  const int c = (q << 7) + colL;
  const bool fin = (p == 0);
  float wreg[128];
#pragma unroll
  for (int i = 0; i < 128; ++i)
    wreg[i] = WT[(size_t)(p * 128 + i) * 512 + c];
  u64* hb = hbuf + b * 1024;

  for (int s = 0; s < 256; ++s) {
    float xwv = 0.f;
    size_t off = 0;
    if (fin) {
      off = (size_t)(b * 256 + s) * 512 + c;
      xwv = XW[off];
    }
    const u32 want = (u32)(s + 1);
    u64 v;
    do {
      v = __hip_atomic_load(&hb[(s & 1) * 512 + tid], __ATOMIC_RELAXED,
                            __HIP_MEMORY_SCOPE_AGENT);
    } while ((u32)(v >> 32) < want);
    hls[s & 1][(tid >> 7) * 132 + (tid & 127)] = __uint_as_float((u32)v);
    __syncthreads();
    const float* hk = &hls[s & 1][p * 132];
    float a0 = 0.f, a1 = 0.f, a2 = 0.f, a3 = 0.f;
#pragma unroll
    for (int i = 0; i < 128; i += 4) {
      a0 = fmaf(wreg[i],     hk[i],     a0);
      a1 = fmaf(wreg[i + 1], hk[i + 1], a1);
      a2 = fmaf(wreg[i + 2], hk[i + 2], a2);
      a3 = fmaf(wreg[i + 3], hk[i + 3], a3);
    }
    float r = (a0 + a1) + (a2 + a3);
    r += __shfl_xor(r, 16);
    r += __shfl_xor(r, 32);
    if (fin) {
      float h = tanhf(r + xwv);
      u64 pk = ((u64)(u32)(s + 2) << 32) | (u64)__float_as_uint(h);
      __hip_atomic_store(&hb[((s + 1) & 1) * 512 + c], pk,
                         __ATOMIC_RELAXED, __HIP_MEMORY_SCOPE_AGENT);
      if (layer) {
        float mv = (s == 0) ? 1.f : (float)mask[b * 255 + s - 1];
        o16a[off] = f2bf(h * mv);
      } else {
        u16 hi = f2bf(h);
        o16a[off] = hi;
        o16b[off] = f2bf(h - bf2f(hi));
      }
    }
  }
}

// ======== fused 25-step edge scan: 256 blocks x 32 rows, zero inter-block sync ========
// Per step: h0' = tanh(xe*e0Wih + b0 + h0@W0^T); h1' = tanh(b1 + h0'@W1^T + h1@W2^T);
// pred = cb + h1'.clsW (in-block reduce). States in swizzled LDS; W streamed per K-tile.
__global__ __launch_bounds__(256, 1) void k_edge_fused(
    const u16* __restrict__ S0,
    const u16* __restrict__ W0b, const u16* __restrict__ W1b, const u16* __restrict__ W2b,
    const float* __restrict__ e0Wih,
    const float* __restrict__ e0bi, const float* __restrict__ e0bh,
    const float* __restrict__ e1bi, const float* __restrict__ e1bh,
    const float* __restrict__ clsW, const float* __restrict__ clsb,
    float* __restrict__ abuf)
{
  __shared__ __attribute__((aligned(16))) u16 h0b[32 * 512];   // granule-XOR swizzled
  __shared__ __attribute__((aligned(16))) u16 h1b[32 * 512];
  __shared__ __attribute__((aligned(16))) u16 Wst[4][128 * 64];
  __shared__ float xesh[32];
  __shared__ float red[4][32];
  const int tid = threadIdx.x;
  const int lane = tid & 63, w = tid >> 6;
  const int lrow = lane & 15, lk = lane >> 4;
  const int r0 = blockIdx.x * 32;
  const int c0 = w * 128;
  const int rsub = lane >> 3;
  const int swz = (((lane & 7) ^ rsub) << 3);   // source granule swizzle (elements)

  // init: h0 = S0 rows (swizzled), h1 = 0, xe = 1
#pragma unroll
  for (int i = 0; i < 8; ++i) {
    int gidx = tid + i * 256;                   // 0..2047 granules (32 rows x 64)
    int row = gidx >> 6, g = gidx & 63;
    short8 v = *(const short8*)(S0 + (size_t)(r0 + row) * 512 + g * 8);
    int sg = g ^ (row & 7);
    *(short8*)(&h0b[row * 512 + sg * 8]) = v;
    short8 z = {0, 0, 0, 0, 0, 0, 0, 0};
    *(short8*)(&h1b[row * 512 + sg * 8]) = z;
  }
  if (tid < 32) xesh[tid] = 1.0f;
  float b0c[8], b1c[8], wihc[8], cwc[8];
#pragma unroll
  for (int nn = 0; nn < 8; ++nn) {
    int col = c0 + nn * 16 + lrow;
    b0c[nn] = e0bi[col] + e0bh[col];
    b1c[nn] = e1bi[col] + e1bh[col];
    wihc[nn] = e0Wih[col];
    cwc[nn] = clsW[col];
  }
  const float cb = clsb[0];
  __syncthreads();

  f32x4 zero4 = {0.f, 0.f, 0.f, 0.f};

  for (int st = 0; st < 25; ++st) {
    // ================= E0: acc = h0 @ W0^T (K = 512) =================
    f32x4 acc[2][8];
#pragma unroll
    for (int mt = 0; mt < 2; ++mt)
#pragma unroll
      for (int nn = 0; nn < 8; ++nn) acc[mt][nn] = zero4;
#pragma unroll 1
    for (int kt = 0; kt < 8; ++kt) {
      asm volatile("s_waitcnt lgkmcnt(0)" ::: "memory");  // prior Wst reads retired
#pragma unroll
      for (int cc = 0; cc < 16; ++cc) {
        int row = cc * 8 + rsub;
        gload16(W0b + (size_t)(c0 + row) * 512 + kt * 64 + swz, &Wst[w][cc * 512]);
      }
      asm volatile("s_waitcnt vmcnt(0)" ::: "memory");    // staging landed
      __builtin_amdgcn_sched_barrier(0);
#pragma unroll
      for (int ks = 0; ks < 2; ++ks) {
        short8 af[2];
#pragma unroll
        for (int mt = 0; mt < 2; ++mt) {
          int arow = mt * 16 + lrow;
          int g = (kt * 8 + ks * 4 + lk) ^ (arow & 7);
          af[mt] = *(const short8*)(&h0b[arow * 512 + g * 8]);
        }
#pragma unroll
        for (int nn = 0; nn < 8; ++nn) {
          int brow = nn * 16 + lrow;
          int kb = (ks * 64 + (lk << 4)) ^ ((brow & 7) << 4);
          short8 bf = *(const short8*)((const char*)&Wst[w][0] + brow * 128 + kb);
#pragma unroll
          for (int mt = 0; mt < 2; ++mt)
            acc[mt][nn] = __builtin_amdgcn_mfma_f32_16x16x32_bf16(af[mt], bf, acc[mt][nn], 0, 0, 0);
        }
      }
    }
    // epilogue E0: h0' = tanh(acc + b0 + xe*wih)
#pragma unroll
    for (int mt = 0; mt < 2; ++mt)
#pragma unroll
      for (int nn = 0; nn < 8; ++nn)
#pragma unroll
        for (int ri = 0; ri < 4; ++ri) {
          int row = mt * 16 + lk * 4 + ri;
          acc[mt][nn][ri] = fast_tanh(acc[mt][nn][ri] + b0c[nn] + xesh[row] * wihc[nn]);
        }
    __syncthreads();                 // all waves done reading h0b
#pragma unroll
    for (int mt = 0; mt < 2; ++mt)
#pragma unroll
      for (int nn = 0; nn < 8; ++nn)
#pragma unroll
        for (int ri = 0; ri < 4; ++ri) {
          int row = mt * 16 + lk * 4 + ri;
          int col = c0 + nn * 16 + lrow;
          int sg = (col >> 3) ^ (row & 7);
          h0b[row * 512 + sg * 8 + (col & 7)] = f2bf(acc[mt][nn][ri]);
        }
    __syncthreads();                 // h0' visible

    // ================= E1: acc = h0' @ W1^T + h1 @ W2^T (K = 1024) =================
#pragma unroll
    for (int mt = 0; mt < 2; ++mt)
#pragma unroll
      for (int nn = 0; nn < 8; ++nn) acc[mt][nn] = zero4;
#pragma unroll 1
    for (int kt = 0; kt < 16; ++kt) {
      const u16* Wsrc = (kt < 8) ? W1b : W2b;
      const u16* Asrc = (kt < 8) ? h0b : h1b;
      int kl = (kt < 8) ? kt : (kt - 8);
      asm volatile("s_waitcnt lgkmcnt(0)" ::: "memory");
#pragma unroll
      for (int cc = 0; cc < 16; ++cc) {
        int row = cc * 8 + rsub;
        gload16(Wsrc + (size_t)(c0 + row) * 512 + kl * 64 + swz, &Wst[w][cc * 512]);
      }
      asm volatile("s_waitcnt vmcnt(0)" ::: "memory");
      __builtin_amdgcn_sched_barrier(0);
#pragma unroll
      for (int ks = 0; ks < 2; ++ks) {
        short8 af[2];
#pragma unroll
        for (int mt = 0; mt < 2; ++mt) {
          int arow = mt * 16 + lrow;
          int g = (kl * 8 + ks * 4 + lk) ^ (arow & 7);
          af[mt] = *(const short8*)(&Asrc[arow * 512 + g * 8]);
        }
#pragma unroll
        for (int nn = 0; nn < 8; ++nn) {
          int brow = nn * 16 + lrow;
          int kb = (ks * 64 + (lk << 4)) ^ ((brow & 7) << 4);
          short8 bf = *(const short8*)((const char*)&Wst[w][0] + brow * 128 + kb);
#pragma unroll
          for (int mt = 0; mt < 2; ++mt)
            acc[mt][nn] = __builtin_amdgcn_mfma_f32_16x16x32_bf16(af[mt], bf, acc[mt][nn], 0, 0, 0);
        }
      }
    }
    // epilogue E1: h1' = tanh(acc + b1); pred partials
    float pp[2][4];
#pragma unroll
    for (int mt = 0; mt < 2; ++mt)
#pragma unroll
      for (int ri = 0; ri < 4; ++ri) pp[mt][ri] = 0.f;
#pragma unroll
    for (int mt = 0; mt < 2; ++mt)
#pragma unroll
      for (int nn = 0; nn < 8; ++nn)
#pragma unroll
        for (int ri = 0; ri < 4; ++ri) {
          float h = fast_tanh(acc[mt][nn][ri] + b1c[nn]);
          acc[mt][nn][ri] = h;
          pp[mt][ri] += h * cwc[nn];
        }
#pragma unroll
    for (int mt = 0; mt < 2; ++mt)
#pragma unroll
      for (int ri = 0; ri < 4; ++ri) {
        float p = pp[mt][ri];
        p += __shfl_xor(p, 1); p += __shfl_xor(p, 2);
        p += __shfl_xor(p, 4); p += __shfl_xor(p, 8);
        pp[mt][ri] = p;
      }
    __syncthreads();                 // all waves done reading h1b
#pragma unroll
    for (int mt = 0; mt < 2; ++mt)
#pragma unroll
      for (int nn = 0; nn < 8; ++nn)
#pragma unroll
        for (int ri = 0; ri < 4; ++ri) {
          int row = mt * 16 + lk * 4 + ri;
          int col = c0 + nn * 16 + lrow;
          int sg = (col >> 3) ^ (row & 7);
          h1b[row * 512 + sg * 8 + (col & 7)] = f2bf(acc[mt][nn][ri]);
        }
    if (lrow == 0) {
#pragma unroll
      for (int mt = 0; mt < 2; ++mt)
#pragma unroll
        for (int ri = 0; ri < 4; ++ri)
          red[w][mt * 16 + lk * 4 + ri] = pp[mt][ri];
    }
    __syncthreads();
    if (tid < 32) {
      float pred = cb + ((red[0][tid] + red[1][tid]) + (red[2][tid] + red[3][tid]));
      xesh[tid] = pred;
      abuf[(size_t)(r0 + tid) * 26 + st + 1] = pred;
    }
    __syncthreads();
  }
}

// ======== Split-precision MFMA GEMM, 128x128 tiles (verified round 19) ========
template<int KD>
__global__ __launch_bounds__(256, 2) void gemm_s(
    const u16* __restrict__ Ahi, const u16* __restrict__ Alo,
    const u16* __restrict__ Whi, const u16* __restrict__ Wlo,
    const float* __restrict__ b1, const float* __restrict__ b2,
    float* __restrict__ outf)
{
  __shared__ __attribute__((aligned(16))) u16 Ah[128 * 64];
  __shared__ __attribute__((aligned(16))) u16 Al[128 * 64];
  __shared__ __attribute__((aligned(16))) u16 Wh[128 * 64];
  __shared__ __attribute__((aligned(16))) u16 Wl[128 * 64];
  const int tid = threadIdx.x;
  const int lane = tid & 63, wid = tid >> 6;
  const int wr = wid >> 1, wc = wid & 1;
  int m0, n0;
  tile_map(blockIdx.x, m0, n0);
  const int rsub = lane >> 3;
  const int swz = (((lane & 7) ^ rsub) << 3);

  f32x4 zero4 = {0.f, 0.f, 0.f, 0.f};
  f32x4 acc[4][4];
#pragma unroll
  for (int i = 0; i < 4; ++i)
#pragma unroll
    for (int j = 0; j < 4; ++j) acc[i][j] = zero4;

  for (int kt = 0; kt < KD / 64; ++kt) {
    __syncthreads();
#pragma unroll
    for (int cc = 0; cc < 4; ++cc) {
      int row = wid * 32 + cc * 8 + rsub;
      size_t ga = (size_t)(m0 + row) * KD + kt * 64 + swz;
      size_t gw = (size_t)(n0 + row) * KD + kt * 64 + swz;
      gload16(Ahi + ga, &Ah[(wid * 32 + cc * 8) * 64]);
      gload16(Alo + ga, &Al[(wid * 32 + cc * 8) * 64]);
      gload16(Whi + gw, &Wh[(wid * 32 + cc * 8) * 64]);
      gload16(Wlo + gw, &Wl[(wid * 32 + cc * 8) * 64]);
    }
    __syncthreads();
#pragma unroll
    for (int ks = 0; ks < 2; ++ks) {
      short8 ah[4], al[4], wh[4], wl[4];
#pragma unroll
      for (int mm = 0; mm < 4; ++mm) {
        int row = wr * 64 + mm * 16 + (lane & 15);
        int kb = (ks * 64 + ((lane >> 4) << 4)) ^ ((row & 7) << 4);
        ah[mm] = *(const short8*)((const char*)Ah + row * 128 + kb);
        al[mm] = *(const short8*)((const char*)Al + row * 128 + kb);
      }
#pragma unroll
      for (int nn = 0; nn < 4; ++nn) {
        int row = wc * 64 + nn * 16 + (lane & 15);
        int kb = (ks * 64 + ((lane >> 4) << 4)) ^ ((row & 7) << 4);
        wh[nn] = *(const short8*)((const char*)Wh + row * 128 + kb);
        wl[nn] = *(const short8*)((const char*)Wl + row * 128 + kb);
      }
#pragma unroll
      for (int mm = 0; mm < 4; ++mm)
#pragma unroll
        for (int nn = 0; nn < 4; ++nn) {
          acc[mm][nn] = __builtin_amdgcn_mfma_f32_16x16x32_bf16(ah[mm], wh[nn], acc[mm][nn], 0, 0, 0);
          acc[mm][nn] = __builtin_amdgcn_mfma_f32_16x16x32_bf16(ah[mm], wl[nn], acc[mm][nn], 0, 0, 0);
          acc[mm][nn] = __builtin_amdgcn_mfma_f32_16x16x32_bf16(al[mm], wh[nn], acc[mm][nn], 0, 0, 0);
        }
    }
  }

  float bcol[4];
#pragma unroll
  for (int nn = 0; nn < 4; ++nn) {
    int col = n0 + wc * 64 + nn * 16 + (lane & 15);
    bcol[nn] = b1[col] + b2[col];
  }
#pragma unroll
  for (int mm = 0; mm < 4; ++mm)
#pragma unroll
    for (int r = 0; r < 4; ++r) {
      int grow = m0 + wr * 64 + mm * 16 + ((lane >> 4) << 2) + r;
#pragma unroll
      for (int nn = 0; nn < 4; ++nn) {
        int col = n0 + wc * 64 + nn * 16 + (lane & 15);
        outf[(size_t)grow * 512 + col] = acc[mm][nn][r] + bcol[nn];
      }
    }
}

// ======== bf16 MFMA GEMM (heads only, MODE 1), 128x128 tiles ========
template<int MODE, int KD>
__global__ __launch_bounds__(256, 2) void gemm_k(
    const u16* __restrict__ Ag, const u16* __restrict__ Ag2,
    const u16* __restrict__ Wg, const u16* __restrict__ W2g,
    const float* __restrict__ b1, const float* __restrict__ b2,
    u16* __restrict__ outb, float* __restrict__ outh, float* __restrict__ outd,
    float* __restrict__ abuf, const float* __restrict__ vecw, int estep)
{
  __shared__ __attribute__((aligned(16))) u16 As[128 * 64];
  __shared__ __attribute__((aligned(16))) u16 Ws[128 * 64];
  const int tid = threadIdx.x;
  const int lane = tid & 63, wid = tid >> 6;
  const int wr = wid >> 1, wc = wid & 1;
  int m0, n0;
  tile_map(blockIdx.x, m0, n0);
  const int rsub = lane >> 3;
  const int swz = (((lane & 7) ^ rsub) << 3);

  f32x4 zero4 = {0.f, 0.f, 0.f, 0.f};
  f32x4 acc[4][4];
#pragma unroll
  for (int i = 0; i < 4; ++i)
#pragma unroll
    for (int j = 0; j < 4; ++j) acc[i][j] = zero4;

  for (int kt = 0; kt < KD / 64; ++kt) {
    const u16* Asrc = Ag; int ka = kt;
    const u16* Wsrc; int kw, rowoff;
    if (n0 >= 256) { Wsrc = W2g; rowoff = n0 - 256; }
    else           { Wsrc = Wg;  rowoff = n0; }
    kw = kt;
    __syncthreads();
#pragma unroll
    for (int cc = 0; cc < 4; ++cc) {
      int row = wid * 32 + cc * 8 + rsub;
      gload16(Asrc + (size_t)(m0 + row) * 512 + ka * 64 + swz, &As[(wid * 32 + cc * 8) * 64]);
      gload16(Wsrc + (size_t)(rowoff + row) * 512 + kw * 64 + swz, &Ws[(wid * 32 + cc * 8) * 64]);
    }
    __syncthreads();
#pragma unroll
    for (int ks = 0; ks < 2; ++ks) {
      short8 af[4], wf[4];
#pragma unroll
      for (int mm = 0; mm < 4; ++mm) {
        int row = wr * 64 + mm * 16 + (lane & 15);
        int kb = (ks * 64 + ((lane >> 4) << 4)) ^ ((row & 7) << 4);
        af[mm] = *(const short8*)((const char*)As + row * 128 + kb);
      }
#pragma unroll
      for (int nn = 0; nn < 4; ++nn) {
        int row = wc * 64 + nn * 16 + (lane & 15);
        int kb = (ks * 64 + ((lane >> 4) << 4)) ^ ((row & 7) << 4);
        wf[nn] = *(const short8*)((const char*)Ws + row * 128 + kb);
      }
#pragma unroll
      for (int mm = 0; mm < 4; ++mm)
#pragma unroll
        for (int nn = 0; nn < 4; ++nn)
          acc[mm][nn] = __builtin_amdgcn_mfma_f32_16x16x32_bf16(af[mm], wf[nn], acc[mm][nn], 0, 0, 0);
    }
  }

  float bcol[4];
#pragma unroll
  for (int nn = 0; nn < 4; ++nn) {
    int col = n0 + wc * 64 + nn * 16 + (lane & 15);
    bcol[nn] = (col < 256) ? b1[col] : b2[col - 256];
  }
#pragma unroll
  for (int mm = 0; mm < 4; ++mm) {
#pragma unroll
    for (int r = 0; r < 4; ++r) {
      int grow = m0 + wr * 64 + mm * 16 + ((lane >> 4) << 2) + r;
#pragma unroll
      for (int nn = 0; nn < 4; ++nn) {
        int col = n0 + wc * 64 + nn * 16 + (lane & 15);
        float v = acc[mm][nn][r] + bcol[nn];
        float e = v > 0.f ? v : (expf(v) - 1.f);
        if (col < 256) outh[(size_t)grow * 256 + col] = e;
        else           outd[(size_t)grow * 256 + (col - 256)] = e;
      }
    }
  }
}

// ---------------- small helpers ----------------
__global__ void k_arc(float* __restrict__ outp, const float* __restrict__ abuf) {
  int idx = blockIdx.x * 256 + threadIdx.x;
  int j = idx & 255, i = (idx >> 8) & 255, b = idx >> 16;
  int k = i - j;
  outp[idx] = (k >= 0 && k <= 25) ? abuf[(size_t)(b * 256 + i) * 26 + k] : 0.0f;
}
__global__ void k_diag(float* __restrict__ outp, float code, int n) {
  int idx = blockIdx.x * 256 + threadIdx.x;
  if (idx < n) outp[idx] = (idx == 0) ? code : 0.0f;
}

extern "C" void kernel_launch(void* const* d_in, const int* in_sizes, int n_in,
                              void* d_out, int out_size, void* d_ws, size_t ws_size,
                              hipStream_t stream) {
  static const int SZ[26] = {6266880, 2088960, 8160, 1024, 524288, 262144, 512, 512,
                             262144, 262144, 512, 512, 512, 262144, 512, 512,
                             262144, 262144, 512, 512, 512, 1, 131072, 256, 131072, 256};
  float diag_code = 0.0f;
  if (n_in != 26) diag_code = 4096.0f + (float)n_in;
  else {
    for (int j = 0; j < 26; ++j)
      if (in_sizes[j] != SZ[j]) { diag_code = 2048.0f + (float)j; break; }
  }
  const size_t NEED = (size_t)(32u << 20);
  if (ws_size < NEED && diag_code == 0.0f) diag_code = 8192.0f;
  if (diag_code != 0.0f) {
    k_diag<<<(out_size + 255) / 256, 256, 0, stream>>>((float*)d_out, diag_code, out_size);
    return;
  }

  const float* inp  = (const float*)d_in[0];
  const float* tag  = (const float*)d_in[1];
  const int*   mask = (const int*)d_in[2];
  const float* sent = (const float*)d_in[3];
  const float* g0_Wih = (const float*)d_in[4];
  const float* g0_Whh = (const float*)d_in[5];
  const float* g0_bih = (const float*)d_in[6];
  const float* g0_bhh = (const float*)d_in[7];
  const float* g1_Wih = (const float*)d_in[8];
  const float* g1_Whh = (const float*)d_in[9];
  const float* g1_bih = (const float*)d_in[10];
  const float* g1_bhh = (const float*)d_in[11];
  const float* e0_Wih = (const float*)d_in[12];
  const float* e0_Whh = (const float*)d_in[13];
  const float* e0_bih = (const float*)d_in[14];
  const float* e0_bhh = (const float*)d_in[15];
  const float* e1_Wih = (const float*)d_in[16];
  const float* e1_Whh = (const float*)d_in[17];
  const float* e1_bih = (const float*)d_in[18];
  const float* e1_bhh = (const float*)d_in[19];
  const float* cls_W  = (const float*)d_in[20];
  const float* cls_b  = (const float*)d_in[21];
  const float* ht_W   = (const float*)d_in[22];
  const float* ht_b   = (const float*)d_in[23];
  const float* dt_W   = (const float*)d_in[24];
  const float* dt_b   = (const float*)d_in[25];

  float* out = (float*)d_out;
  char*  ob  = (char*)d_out;
  char*  ws  = (char*)d_ws;

  // ---- d_out overlays ----
  u16*  W0hi = (u16*)(ob);
  u16*  W0lo = (u16*)(ob + (1u << 20));
  float* XW0 = (float*)(ob + (2u << 20));
  float* WT0 = (float*)(ob + (18u << 20));
  float* WT1 = (float*)(ob + (19u << 20));
  u16*  G1hi = (u16*)(ob + (20u << 20));
  u16*  G1lo = (u16*)(ob + (20u << 20) + (512u << 10));
  // ---- ws overlays ----
  u16*  Xhi  = (u16*)(ws);
  u16*  Xlo  = (u16*)(ws + (16u << 20));
  u16*  Y0hi = (u16*)(ws);
  u16*  Y0lo = (u16*)(ws + (8u << 20));
  u16*  S0   = Y0hi;
  float* ABUF = (float*)(ws + (24u << 20));
  u16*  W0b  = (u16*)(ws + (25u << 20));
  u16*  W1b  = (u16*)(ws + (25u << 20) + (512u << 10));
  u16*  W2b  = (u16*)(ws + (26u << 20));
  u16*  W3b  = (u16*)(ws + (26u << 20) + (512u << 10));
  u16*  W4b  = (u16*)(ws + (26u << 20) + (768u << 10));
  u64*  HBUF = (u64*)(ws + (28u << 20));

  // 1) prep1
  k_prep1<<<37888, 256, 0, stream>>>(Xhi, Xlo, inp, tag, sent,
                                     W0hi, W0lo, g0_Wih, WT0, g0_Whh, WT1, g1_Whh,
                                     G1hi, G1lo, g1_Wih);
  // 2) xW0 -> XW0
  gemm_s<1024><<<256, 256, 0, stream>>>(Xhi, Xlo, W0hi, W0lo, g0_bih, g0_bhh, XW0);
  // 3) prep2
  k_prep2<<<5056, 256, 0, stream>>>(HBUF, W0b, e0_Whh, W1b, e1_Wih, W2b, e1_Whh,
                                    W3b, ht_W, W4b, dt_W, ABUF, cls_b);
  // 4) scan0 -> Y0 hi/lo
  k_gscan_mb<<<128, 512, 0, stream>>>(XW0, WT0, mask, 0, HBUF, Y0hi, Y0lo);
  // 5) xW1 -> XW0
  gemm_s<512><<<256, 256, 0, stream>>>(Y0hi, Y0lo, G1hi, G1lo, g1_bih, g1_bhh, XW0);
  // 6) prep3 (HBUF re-init)
  k_prep3<<<128, 256, 0, stream>>>(HBUF);
  // 7) scan1 -> S0 (masked bf16)
  k_gscan_mb<<<128, 512, 0, stream>>>(XW0, WT1, mask, 1, HBUF, S0, nullptr);
  // 8) tag heads
  gemm_k<1, 512><<<256, 256, 0, stream>>>(S0, nullptr, W3b, W4b, ht_b, dt_b,
                                          nullptr, out + 2097152, out + 4194304,
                                          nullptr, nullptr, 0);
  // 9) fused 25-step edge scan
  k_edge_fused<<<256, 256, 0, stream>>>(S0, W0b, W1b, W2b, e0_Wih,
                                        e0_bih, e0_bhh, e1_bih, e1_bhh,
                                        cls_W, cls_b, ABUF);
  // 10) arc gather
  k_arc<<<8192, 256, 0, stream>>>(out, ABUF);
}